// Round 9
// baseline (781.411 us; speedup 1.0000x reference)
//
#include <hip/hip_runtime.h>
#include <hip/hip_bf16.h>
#include <math.h>

// ---------------------------------------------------------------------------
// GPoolBlock, round 9: round-8 structure with staging-base fix.
//  - BK=64 stages (2 K-chunks per barrier) -> half the barrier drains
//  - 4-wave blocks (128x128 tile) -> 2 blocks/CU co-resident (overlap drains)
//  - global pixel-space M-tiling: 722 tiles x 128 rows = 92416 exactly
//  - staging base = receptive-field CORNER (p/WW)*21+(p%WW), NOT center
//    (round-8 bug: center base shifted every conv window by +1,+1)
//  - all frag register arrays compile-time indexed (round-6 spill lesson)
// ---------------------------------------------------------------------------

#define BATCH   256
#define TRUNK_C 256
#define REG_C   192
#define GPOOL_C 64
#define HH      19
#define WW      19
#define HW      361
#define PP      441          // 21*21 padded pixels
#define NPX     (BATCH * HW) // 92416 global pixels = 722 * 128
#define EPS     1e-5f

typedef __hip_bfloat16 bf16;
typedef __attribute__((ext_vector_type(8))) short short8;
typedef __attribute__((ext_vector_type(4))) float floatx4;

__device__ __forceinline__ float b2f(bf16 v) { return __bfloat162float(v); }
__device__ __forceinline__ bf16  f2b(float v) { return __float2bfloat16(v); }

__device__ __forceinline__ float mish_f(float v) {
    float sp = (v > 20.0f) ? v : log1pf(expf(v));
    return v * tanhf(sp);
}

__device__ __forceinline__ void gload_lds16(const void* gsrc, void* lds) {
    __builtin_amdgcn_global_load_lds(
        (const __attribute__((address_space(1))) void*)gsrc,
        (__attribute__((address_space(3))) void*)lds, 16, 0, 0);
}

// --------------------------- prep: fold BN params ---------------------------
// bnbuf: [0:256] bn1_s [256:512] bn1_b [512:576] bn1b_s [576:640] bn1b_b
//        [640:832] bn2_s [832:1024] bn2_b
__global__ void prep_bn_kernel(const float* g1, const float* b1, const float* m1, const float* v1,
                               const float* g1b, const float* b1b, const float* m1b, const float* v1b,
                               const float* g2, const float* b2, const float* m2, const float* v2,
                               float* bnbuf) {
    int t = threadIdx.x;
    if (t < 256) {
        float s = g1[t] / sqrtf(v1[t] + EPS);
        bnbuf[t] = s;
        bnbuf[256 + t] = b1[t] - m1[t] * s;
    } else if (t < 320) {
        int c = t - 256;
        float s = g1b[c] / sqrtf(v1b[c] + EPS);
        bnbuf[512 + c] = s;
        bnbuf[576 + c] = b1b[c] - m1b[c] * s;
    } else if (t < 512) {
        int c = t - 320;
        float s = g2[c] / sqrtf(v2[c] + EPS);
        bnbuf[640 + c] = s;
        bnbuf[832 + c] = b2[c] - m2[c] * s;
    }
}

// ------------- prep: weights -> MFMA-fragment layout (bf16) -----------------
// w1c_p[((cog*72 + kc)*64 + lane)*8 + j]: co = cog*16 + (lane&15),
//   k = kc*32 + (lane>>4)*8 + j, r = k>>8, ci = k&255; co<192 -> w1a else w1b.
// w2_p analogous with K=1728 (kc 54), CIN=192.
__global__ void prep_w_kernel(const float* __restrict__ w1a, const float* __restrict__ w1b,
                              const float* __restrict__ w2,
                              bf16* __restrict__ w1c_p, bf16* __restrict__ w2_p) {
    const int T1 = 16 * 72 * 64 * 8;     // 589824
    const int T2 = 16 * 54 * 64 * 8;     // 442368
    for (int i = blockIdx.x * blockDim.x + threadIdx.x; i < T1 + T2;
         i += gridDim.x * blockDim.x) {
        if (i < T1) {
            int j = i & 7, lane = (i >> 3) & 63;
            int kc = (i >> 9) % 72, cog = (i >> 9) / 72;
            int co = cog * 16 + (lane & 15);
            int k = kc * 32 + ((lane >> 4) << 3) + j;
            int r = k >> 8, ci = k & 255;
            float v = (co < 192) ? w1a[co * 2304 + ci * 9 + r]
                                 : w1b[(co - 192) * 2304 + ci * 9 + r];
            w1c_p[i] = f2b(v);
        } else {
            int i2 = i - T1;
            int j = i2 & 7, lane = (i2 >> 3) & 63;
            int kc = (i2 >> 9) % 54, cog = (i2 >> 9) / 54;
            int co = cog * 16 + (lane & 15);
            int k = kc * 32 + ((lane >> 4) << 3) + j;
            int r = k / 192, ci = k % 192;
            w2_p[i2] = f2b(w2[co * 1728 + ci * 9 + r]);
        }
    }
}

// ---------------- zero the padded borders of act_pad and reg_pad ------------
__global__ void zero_border_kernel(bf16* __restrict__ act_pad, bf16* __restrict__ reg_pad) {
    int b = blockIdx.x;
    int t = threadIdx.x;     // 256
    for (int pp = 0; pp < PP; ++pp) {
        int r = pp / 21, c = pp % 21;
        bool border = (r == 0) | (r == 20) | (c == 0) | (c == 20);
        if (!border) continue;
        act_pad[((size_t)b * PP + pp) * TRUNK_C + t] = f2b(0.0f);
        if (t < REG_C) reg_pad[((size_t)b * PP + pp) * REG_C + t] = f2b(0.0f);
    }
}

// ------- bn1+mish + LDS transpose: x [b][256][361] fp32 -> act_pad CL bf16 --
__global__ __launch_bounds__(256)
void bn1_mish_t_kernel(const float* __restrict__ x, const float* __restrict__ bnbuf,
                       bf16* __restrict__ act_pad) {
    __shared__ float lds[256][32];    // XOR-swizzled columns
    int pc = blockIdx.x;              // pixel chunk of 32 (12 chunks)
    int b  = blockIdx.y;
    int t  = threadIdx.x;
    int p0 = pc * 32;
    int px = t & 31;
#pragma unroll
    for (int it = 0; it < 32; ++it) {          // 32 passes x 8 channels = 256
        int ci = it * 8 + (t >> 5);
        int p  = p0 + px;
        float v = 0.0f;
        if (p < HW) v = x[((size_t)b * TRUNK_C + ci) * HW + p];
        v = v * bnbuf[ci] + bnbuf[256 + ci];
        lds[ci][px ^ (ci >> 3)] = mish_f(v);
    }
    __syncthreads();
#pragma unroll
    for (int it = 0; it < 4; ++it) {
        int pl = it * 8 + (t >> 5);
        int p  = p0 + pl;
        if (p >= HW) continue;
        int ch = t & 31;
        short8 vv;
#pragma unroll
        for (int j = 0; j < 8; ++j) {
            bf16 h = f2b(lds[ch * 8 + j][pl ^ ch]);
            short s;
            __builtin_memcpy(&s, &h, 2);
            vv[j] = s;
        }
        int pp = (p / WW + 1) * 21 + (p % WW + 1);
        *(short8*)(act_pad + ((size_t)b * PP + pp) * TRUNK_C + ch * 8) = vv;
    }
}

// ---------------------- conv1 fused (act x W -> 256 co) ---------------------
// Grid: (722 px-tiles, 2 co-halves). Block: 256 thr = 4 waves (mi x niw).
// Tile: 128 px x 128 co, BK=64 (36 stages). A-tile 16KB double-buffered.
__global__ __launch_bounds__(256)
void conv1_kernel(const bf16* __restrict__ act,     // [b][441][256]
                  const bf16* __restrict__ wfrag,   // [16][72][64][8]
                  bf16* __restrict__ reg_out,       // [b][441][192]
                  bf16* __restrict__ gp_out,        // [b][361][64]
                  const float* __restrict__ ep_scale, const float* __restrict__ ep_bias) {
    const int CIN = 256, NS = 36;
    __shared__ __align__(16) bf16 atile0[128 * 64];
    __shared__ __align__(16) bf16 atile1[128 * 64];
    const int tile = blockIdx.x;
    const int nb   = blockIdx.y;
    const int t    = threadIdx.x;
    const int w    = t >> 6, lane = t & 63;
    const int mi   = w >> 1, niw = w & 1;
    const int l15  = lane & 15, quad = lane >> 4;

    // staging sources: 4 granule-loads/thread/stage; granule L=(i*4+w)*64+lane
    // base = receptive-field CORNER in padded coords: (p/WW)*21 + (p%WW)
    const bf16* sg[4];
#pragma unroll
    for (int i = 0; i < 4; ++i) {
        int L = (i * 4 + w) * 64 + lane;
        int row = L >> 3, gpr = L & 7;
        int g = gpr ^ (row & 7);
        int px = tile * 128 + row;
        int b = px / HW, p = px - b * HW;
        sg[i] = act + ((size_t)b * PP + (p / WW) * 21 + (p % WW)) * CIN + g * 8;
    }
    auto stage = [&](bf16* buf, int kcs) {
        int r = kcs >> 2, c = kcs & 3;           // CIN=256 -> 4 ci64 per tap
        int off = ((r / 3) * 21 + (r % 3)) * CIN + (c << 6);
#pragma unroll
        for (int i = 0; i < 4; ++i)
            gload_lds16(sg[i] + off, buf + ((i * 4 + w) << 9));
    };

    // B-frag bases: cog = nb*8 + niw*4 + ns
    const bf16* wb[4];
#pragma unroll
    for (int ns = 0; ns < 4; ++ns)
        wb[ns] = wfrag + ((size_t)(nb * 8 + niw * 4 + ns) * 72 * 64 + lane) * 8;

    // A-frag LDS offsets (row-swizzled granules)
    int aoff[4][2];
#pragma unroll
    for (int ms = 0; ms < 4; ++ms) {
        int row = mi * 64 + ms * 16 + l15;
#pragma unroll
        for (int s = 0; s < 2; ++s)
            aoff[ms][s] = row * 64 + (((s * 4 + quad) ^ (row & 7)) << 3);
    }

    floatx4 acc[4][4];
#pragma unroll
    for (int i = 0; i < 4; ++i)
#pragma unroll
        for (int j = 0; j < 4; ++j) acc[i][j] = (floatx4){0.f, 0.f, 0.f, 0.f};

    short8 af[4], wA0[4], wA1[4], wB0[4], wB1[4];
    stage(atile0, 0);
#pragma unroll
    for (int ns = 0; ns < 4; ++ns) {
        wA0[ns] = *(const short8*)(wb[ns]);
        wA1[ns] = *(const short8*)(wb[ns] + 512);
    }

    for (int k = 0; k < NS; k += 2) {
        // ---- even stage: atile0, wA ----
        __syncthreads();
        if (k + 1 < NS) {
            stage(atile1, k + 1);
#pragma unroll
            for (int ns = 0; ns < 4; ++ns) {
                wB0[ns] = *(const short8*)(wb[ns] + (size_t)(k + 1) * 1024);
                wB1[ns] = *(const short8*)(wb[ns] + (size_t)(k + 1) * 1024 + 512);
            }
        }
#pragma unroll
        for (int ms = 0; ms < 4; ++ms) af[ms] = *(const short8*)(atile0 + aoff[ms][0]);
#pragma unroll
        for (int ms = 0; ms < 4; ++ms)
#pragma unroll
            for (int ns = 0; ns < 4; ++ns)
                acc[ms][ns] = __builtin_amdgcn_mfma_f32_16x16x32_bf16(af[ms], wA0[ns], acc[ms][ns], 0, 0, 0);
#pragma unroll
        for (int ms = 0; ms < 4; ++ms) af[ms] = *(const short8*)(atile0 + aoff[ms][1]);
#pragma unroll
        for (int ms = 0; ms < 4; ++ms)
#pragma unroll
            for (int ns = 0; ns < 4; ++ns)
                acc[ms][ns] = __builtin_amdgcn_mfma_f32_16x16x32_bf16(af[ms], wA1[ns], acc[ms][ns], 0, 0, 0);

        // ---- odd stage: atile1, wB ----
        if (k + 1 < NS) {
            __syncthreads();
            if (k + 2 < NS) {
                stage(atile0, k + 2);
#pragma unroll
                for (int ns = 0; ns < 4; ++ns) {
                    wA0[ns] = *(const short8*)(wb[ns] + (size_t)(k + 2) * 1024);
                    wA1[ns] = *(const short8*)(wb[ns] + (size_t)(k + 2) * 1024 + 512);
                }
            }
#pragma unroll
            for (int ms = 0; ms < 4; ++ms) af[ms] = *(const short8*)(atile1 + aoff[ms][0]);
#pragma unroll
            for (int ms = 0; ms < 4; ++ms)
#pragma unroll
                for (int ns = 0; ns < 4; ++ns)
                    acc[ms][ns] = __builtin_amdgcn_mfma_f32_16x16x32_bf16(af[ms], wB0[ns], acc[ms][ns], 0, 0, 0);
#pragma unroll
            for (int ms = 0; ms < 4; ++ms) af[ms] = *(const short8*)(atile1 + aoff[ms][1]);
#pragma unroll
            for (int ms = 0; ms < 4; ++ms)
#pragma unroll
                for (int ns = 0; ns < 4; ++ns)
                    acc[ms][ns] = __builtin_amdgcn_mfma_f32_16x16x32_bf16(af[ms], wB1[ns], acc[ms][ns], 0, 0, 0);
        }
    }

    // epilogue: D rows = px (quad*4+rg), cols = co (l15)
    const bool isgp = (nb == 1) && (niw == 1);   // cogs 12..15 -> co 192..255
    float scl[4], bia[4];
    if (isgp) {
#pragma unroll
        for (int ns = 0; ns < 4; ++ns) {
            int cg = ns * 16 + l15;
            scl[ns] = ep_scale[cg]; bia[ns] = ep_bias[cg];
        }
    }
#pragma unroll
    for (int ms = 0; ms < 4; ++ms) {
#pragma unroll
        for (int rg = 0; rg < 4; ++rg) {
            int px = tile * 128 + mi * 64 + ms * 16 + quad * 4 + rg;
            int b = px / HW, p = px - b * HW;
            if (isgp) {
                size_t base = ((size_t)b * HW + p) * GPOOL_C;
#pragma unroll
                for (int ns = 0; ns < 4; ++ns) {
                    float v = acc[ms][ns][rg];
                    v = mish_f(v * scl[ns] + bia[ns]);
                    gp_out[base + ns * 16 + l15] = f2b(v);
                }
            } else {
                size_t ppad = (size_t)b * PP + (p / WW + 1) * 21 + (p % WW + 1);
#pragma unroll
                for (int ns = 0; ns < 4; ++ns) {
                    int co = (nb * 8 + niw * 4 + ns) * 16 + l15;
                    reg_out[ppad * REG_C + co] = f2b(acc[ms][ns][rg]);
                }
            }
        }
    }
}

// ------------------- conv2 (W x act -> channel-first fp32) ------------------
// Grid: (722 px-tiles, 2 co-halves). Block: 256 thr = 4 waves (pw x cw).
// Tile: 128 co x 128 px, BK=64 (27 stages). act tile staged like conv1.
__global__ __launch_bounds__(256)
void conv2_kernel(const bf16* __restrict__ act,     // reg_pad [b][441][192]
                  const bf16* __restrict__ wfrag,   // [16][54][64][8]
                  const float* __restrict__ resid,
                  float* __restrict__ out) {
    const int CIN = 192, NS = 27;
    __shared__ __align__(16) bf16 atile0[128 * 64];
    __shared__ __align__(16) bf16 atile1[128 * 64];
    const int tile = blockIdx.x;
    const int nb   = blockIdx.y;
    const int t    = threadIdx.x;
    const int w    = t >> 6, lane = t & 63;
    const int pw   = w >> 1, cw = w & 1;
    const int l15  = lane & 15, quad = lane >> 4;

    // staging base = receptive-field CORNER: (p/WW)*21 + (p%WW)
    const bf16* sg[4];
#pragma unroll
    for (int i = 0; i < 4; ++i) {
        int L = (i * 4 + w) * 64 + lane;
        int row = L >> 3, gpr = L & 7;
        int g = gpr ^ (row & 7);
        int px = tile * 128 + row;
        int b = px / HW, p = px - b * HW;
        sg[i] = act + ((size_t)b * PP + (p / WW) * 21 + (p % WW)) * CIN + g * 8;
    }
    auto stage = [&](bf16* buf, int kcs) {
        int r = kcs / 3, c = kcs - r * 3;        // CIN=192 -> 3 ci64 per tap
        int off = ((r / 3) * 21 + (r % 3)) * CIN + (c << 6);
#pragma unroll
        for (int i = 0; i < 4; ++i)
            gload_lds16(sg[i] + off, buf + ((i * 4 + w) << 9));
    };

    // A-frag (weight) bases: cog = nb*8 + cw*4 + ms
    const bf16* wb[4];
#pragma unroll
    for (int ms = 0; ms < 4; ++ms)
        wb[ms] = wfrag + ((size_t)(nb * 8 + cw * 4 + ms) * 54 * 64 + lane) * 8;

    // B-frag (act) LDS offsets
    int aoff[4][2];
#pragma unroll
    for (int ns = 0; ns < 4; ++ns) {
        int row = pw * 64 + ns * 16 + l15;
#pragma unroll
        for (int s = 0; s < 2; ++s)
            aoff[ns][s] = row * 64 + (((s * 4 + quad) ^ (row & 7)) << 3);
    }

    floatx4 acc[4][4];
#pragma unroll
    for (int i = 0; i < 4; ++i)
#pragma unroll
        for (int j = 0; j < 4; ++j) acc[i][j] = (floatx4){0.f, 0.f, 0.f, 0.f};

    short8 bf_[4], wA0[4], wA1[4], wB0[4], wB1[4];
    stage(atile0, 0);
#pragma unroll
    for (int ms = 0; ms < 4; ++ms) {
        wA0[ms] = *(const short8*)(wb[ms]);
        wA1[ms] = *(const short8*)(wb[ms] + 512);
    }

    for (int k = 0; k < NS; k += 2) {
        // ---- even stage: atile0, wA ----
        __syncthreads();
        if (k + 1 < NS) {
            stage(atile1, k + 1);
#pragma unroll
            for (int ms = 0; ms < 4; ++ms) {
                wB0[ms] = *(const short8*)(wb[ms] + (size_t)(k + 1) * 1024);
                wB1[ms] = *(const short8*)(wb[ms] + (size_t)(k + 1) * 1024 + 512);
            }
        }
#pragma unroll
        for (int ns = 0; ns < 4; ++ns) bf_[ns] = *(const short8*)(atile0 + aoff[ns][0]);
#pragma unroll
        for (int ms = 0; ms < 4; ++ms)
#pragma unroll
            for (int ns = 0; ns < 4; ++ns)
                acc[ms][ns] = __builtin_amdgcn_mfma_f32_16x16x32_bf16(wA0[ms], bf_[ns], acc[ms][ns], 0, 0, 0);
#pragma unroll
        for (int ns = 0; ns < 4; ++ns) bf_[ns] = *(const short8*)(atile0 + aoff[ns][1]);
#pragma unroll
        for (int ms = 0; ms < 4; ++ms)
#pragma unroll
            for (int ns = 0; ns < 4; ++ns)
                acc[ms][ns] = __builtin_amdgcn_mfma_f32_16x16x32_bf16(wA1[ms], bf_[ns], acc[ms][ns], 0, 0, 0);

        // ---- odd stage: atile1, wB ----
        if (k + 1 < NS) {
            __syncthreads();
            if (k + 2 < NS) {
                stage(atile0, k + 2);
#pragma unroll
                for (int ms = 0; ms < 4; ++ms) {
                    wA0[ms] = *(const short8*)(wb[ms] + (size_t)(k + 2) * 1024);
                    wA1[ms] = *(const short8*)(wb[ms] + (size_t)(k + 2) * 1024 + 512);
                }
            }
#pragma unroll
            for (int ns = 0; ns < 4; ++ns) bf_[ns] = *(const short8*)(atile1 + aoff[ns][0]);
#pragma unroll
            for (int ms = 0; ms < 4; ++ms)
#pragma unroll
                for (int ns = 0; ns < 4; ++ns)
                    acc[ms][ns] = __builtin_amdgcn_mfma_f32_16x16x32_bf16(wB0[ms], bf_[ns], acc[ms][ns], 0, 0, 0);
#pragma unroll
            for (int ns = 0; ns < 4; ++ns) bf_[ns] = *(const short8*)(atile1 + aoff[ns][1]);
#pragma unroll
            for (int ms = 0; ms < 4; ++ms)
#pragma unroll
                for (int ns = 0; ns < 4; ++ns)
                    acc[ms][ns] = __builtin_amdgcn_mfma_f32_16x16x32_bf16(wB1[ms], bf_[ns], acc[ms][ns], 0, 0, 0);
        }
    }

    // epilogue: D rows = co (quad*4+rg), cols = px (l15)
#pragma unroll
    for (int ns = 0; ns < 4; ++ns) {
        int px = tile * 128 + pw * 64 + ns * 16 + l15;
        int b = px / HW, p = px - b * HW;
#pragma unroll
        for (int ms = 0; ms < 4; ++ms) {
#pragma unroll
            for (int rg = 0; rg < 4; ++rg) {
                int co = (nb * 8 + cw * 4 + ms) * 16 + quad * 4 + rg;
                size_t idx = ((size_t)b * TRUNK_C + co) * HW + p;
                out[idx] = acc[ms][ns][rg] + resid[idx];
            }
        }
    }
}

// ------------------------------ kata gpool ----------------------------------
__global__ void gpool_kernel(const bf16* __restrict__ gp, float* __restrict__ pooled) {
    __shared__ float ls[4][64], lm[4][64];
    int b = blockIdx.x;
    int t = threadIdx.x;          // 256
    int c = t & 63, sub = t >> 6;
    float s = 0.0f, mx = -1e30f;
    for (int p = sub; p < HW; p += 4) {
        float v = b2f(gp[((size_t)b * HW + p) * GPOOL_C + c]);
        s += v;
        mx = fmaxf(mx, v);
    }
    ls[sub][c] = s; lm[sub][c] = mx;
    __syncthreads();
    if (t < 64) {
        float ss = ls[0][t] + ls[1][t] + ls[2][t] + ls[3][t];
        float mm = fmaxf(fmaxf(lm[0][t], lm[1][t]), fmaxf(lm[2][t], lm[3][t]));
        float mean = ss * (1.0f / 361.0f);
        pooled[b * 192 + t] = mean;
        pooled[b * 192 + 64 + t] = mean * 0.5f;
        pooled[b * 192 + 128 + t] = mm;
    }
}

// -------------------------- tiny linear (192x192) ---------------------------
__global__ void lin_kernel(const float* __restrict__ pooled, const float* __restrict__ w_lin,
                           float* __restrict__ gpout) {
    int i = blockIdx.x * blockDim.x + threadIdx.x;
    if (i >= BATCH * REG_C) return;
    int b = i / REG_C;
    int oc = i - b * REG_C;
    const float* pr = pooled + b * 192;
    const float* wr = w_lin + oc * 192;
    float s = 0.0f;
    for (int j = 0; j < 192; ++j) s = fmaf(pr[j], wr[j], s);
    gpout[i] = s;
}

// ------------- add gpool bias + bn2 + mish, in-place on reg_pad -------------
__global__ void add_bn2_mish_kernel(bf16* __restrict__ reg_pad, const float* __restrict__ gpout,
                                    const float* __restrict__ bnbuf) {
    const int n = BATCH * HW * REG_C;
    int i = blockIdx.x * blockDim.x + threadIdx.x;
    if (i >= n) return;
    int c = i % REG_C;
    int bp = i / REG_C;
    int p = bp % HW;
    int b = bp / HW;
    int pp = (p / WW + 1) * 21 + (p % WW + 1);
    size_t idx = ((size_t)b * PP + pp) * REG_C + c;
    float v = b2f(reg_pad[idx]) + gpout[b * 192 + c];
    v = v * bnbuf[640 + c] + bnbuf[832 + c];
    reg_pad[idx] = f2b(mish_f(v));
}

// ---------------------------------------------------------------------------
extern "C" void kernel_launch(void* const* d_in, const int* in_sizes, int n_in,
                              void* d_out, int out_size, void* d_ws, size_t ws_size,
                              hipStream_t stream) {
    const float* x     = (const float*)d_in[0];
    const float* bn1_g = (const float*)d_in[1];
    const float* bn1_b = (const float*)d_in[2];
    const float* bn1_m = (const float*)d_in[3];
    const float* bn1_v = (const float*)d_in[4];
    const float* w1a   = (const float*)d_in[5];
    const float* w1b   = (const float*)d_in[6];
    const float* bn1b_g = (const float*)d_in[7];
    const float* bn1b_b = (const float*)d_in[8];
    const float* bn1b_m = (const float*)d_in[9];
    const float* bn1b_v = (const float*)d_in[10];
    const float* w_lin  = (const float*)d_in[11];
    const float* bn2_g  = (const float*)d_in[12];
    const float* bn2_b  = (const float*)d_in[13];
    const float* bn2_m  = (const float*)d_in[14];
    const float* bn2_v  = (const float*)d_in[15];
    const float* w2     = (const float*)d_in[16];
    float* out = (float*)d_out;

    char* ws = (char*)d_ws;
    size_t off = 0;
    auto alloc = [&](size_t bytes) {
        void* p = ws + off;
        off += (bytes + 255) & ~(size_t)255;
        return p;
    };
    bf16*  act_pad = (bf16*)alloc((size_t)BATCH * PP * TRUNK_C * sizeof(bf16));
    bf16*  reg_pad = (bf16*)alloc((size_t)BATCH * PP * REG_C * sizeof(bf16));
    bf16*  gp      = (bf16*)alloc((size_t)BATCH * HW * GPOOL_C * sizeof(bf16));
    bf16*  w1c_p   = (bf16*)alloc((size_t)16 * 72 * 64 * 8 * sizeof(bf16));
    bf16*  w2_p    = (bf16*)alloc((size_t)16 * 54 * 64 * 8 * sizeof(bf16));
    float* pooled  = (float*)alloc((size_t)BATCH * 192 * sizeof(float));
    float* gpout   = (float*)alloc((size_t)BATCH * 192 * sizeof(float));
    float* bnbuf   = (float*)alloc(1024 * sizeof(float));
    (void)ws_size;

    // 1. prep
    hipLaunchKernelGGL(prep_bn_kernel, dim3(1), dim3(512), 0, stream,
                       bn1_g, bn1_b, bn1_m, bn1_v,
                       bn1b_g, bn1b_b, bn1b_m, bn1b_v,
                       bn2_g, bn2_b, bn2_m, bn2_v, bnbuf);
    hipLaunchKernelGGL(prep_w_kernel, dim3(1024), dim3(256), 0, stream,
                       w1a, w1b, w2, w1c_p, w2_p);
    hipLaunchKernelGGL(zero_border_kernel, dim3(BATCH), dim3(256), 0, stream,
                       act_pad, reg_pad);

    // 2. act_pad = mish(bn1(x)), LDS-tiled transpose to channel-last padded
    hipLaunchKernelGGL(bn1_mish_t_kernel, dim3(12, BATCH), dim3(256), 0, stream,
                       x, bnbuf, act_pad);

    // 3. fused conv1: reg_pad raw interior + gp = mish(bn1b(conv))
    hipLaunchKernelGGL(conv1_kernel, dim3(NPX / 128, 2), dim3(256), 0, stream,
                       act_pad, w1c_p, reg_pad, gp, bnbuf + 512, bnbuf + 576);

    // 4. pooled = kata_gpool(gp); gpout = pooled @ w_lin^T
    hipLaunchKernelGGL(gpool_kernel, dim3(BATCH), dim3(256), 0, stream, gp, pooled);
    hipLaunchKernelGGL(lin_kernel, dim3((BATCH * REG_C + 255) / 256), dim3(256), 0, stream,
                       pooled, w_lin, gpout);

    // 5. reg_pad = mish(bn2(reg_pad + gpout)) in-place (interior only)
    {
        int n = BATCH * HW * REG_C;
        hipLaunchKernelGGL(add_bn2_mish_kernel, dim3((n + 255) / 256), dim3(256), 0, stream,
                           reg_pad, gpout, bnbuf);
    }

    // 6. out = conv(reg_pad, w2) + x, channel-first fp32
    hipLaunchKernelGGL(conv2_kernel, dim3(NPX / 128, 2), dim3(256), 0, stream,
                       reg_pad, w2_p, x, out);
}